// Round 1
// baseline (1303.552 us; speedup 1.0000x reference)
//
#include <hip/hip_runtime.h>
#include <math.h>

#define NPTS 65536
#define BATCH 32

// ---------------- stage 1: gather + 3-tap smoothing + tanh ----------------
// out[b][c][n] = tanh( sum_k x[b, ord[clip(n-1+k)], c] * sp_w[n,k] + sp_b[n] )
__global__ void smooth_kernel(const float* __restrict__ x,
                              const int* __restrict__ ord,
                              const float* __restrict__ sp_w,
                              const float* __restrict__ sp_b,
                              float* __restrict__ out)
{
    int idx = blockIdx.x * blockDim.x + threadIdx.x; // b*N + n
    if (idx >= BATCH * NPTS) return;
    int b = idx / NPTS;
    int n = idx - b * NPTS;
    int nm = (n > 0) ? n - 1 : 0;
    int np = (n < NPTS - 1) ? n + 1 : NPTS - 1;
    int i0 = ord[nm], i1 = ord[n], i2 = ord[np];
    float w0 = sp_w[n * 3 + 0], w1 = sp_w[n * 3 + 1], w2 = sp_w[n * 3 + 2];
    float bb = sp_b[n];
    const float* xb = x + (size_t)b * NPTS * 2;
    float2 v0 = *(const float2*)(xb + (size_t)i0 * 2);
    float2 v1 = *(const float2*)(xb + (size_t)i1 * 2);
    float2 v2 = *(const float2*)(xb + (size_t)i2 * 2);
    float c0 = tanhf(v0.x * w0 + v1.x * w1 + v2.x * w2 + bb);
    float c1 = tanhf(v0.y * w0 + v1.y * w1 + v2.y * w2 + bb);
    out[((size_t)b * 2 + 0) * NPTS + n] = c0;
    out[((size_t)b * 2 + 1) * NPTS + n] = c1;
}

// ---------------- strided conv1d + bias + tanh ----------------
// out[b*out_bstride + co*LOUT + l] = tanh(bias[co] + sum_{ci,k} in[b,ci, 4l-16+k] * w[co,ci,k])
template <int CIN, int COUT, int LIN, int LOUT>
__global__ void conv_kernel(const float* __restrict__ in,
                            const float* __restrict__ w,
                            const float* __restrict__ bias,
                            float* __restrict__ out,
                            int out_bstride)
{
    int idx = blockIdx.x * blockDim.x + threadIdx.x;
    if (idx >= BATCH * COUT * LOUT) return;
    int l = idx % LOUT;
    int t = idx / LOUT;
    int co = t % COUT;
    int b = t / COUT;
    float acc = bias[co];
    int base = l * 4 - 16;
    const float* inb = in + (size_t)b * CIN * LIN;
    const float* wc = w + (size_t)co * CIN * 32;
#pragma unroll
    for (int ci = 0; ci < CIN; ++ci) {
        const float* inc = inb + (size_t)ci * LIN;
        const float* wk = wc + ci * 32;
#pragma unroll
        for (int k = 0; k < 32; ++k) {
            int pos = base + k;
            if (pos >= 0 && pos < LIN) acc += inc[pos] * wk[k];
        }
    }
    out[(size_t)b * out_bstride + co * LOUT + l] = tanhf(acc);
}

// ---------------- fc1: (B,2080) @ (128,2080)^T + b -> tanh -> (B,128) ----------------
__global__ void fc1_kernel(const float* __restrict__ h,
                           const float* __restrict__ w,
                           const float* __restrict__ bias,
                           float* __restrict__ out)
{
    int b = blockIdx.x;   // 32
    int j = threadIdx.x;  // 128
    const float* hb = h + (size_t)b * 2080;
    const float* wj = w + (size_t)j * 2080;
    float acc = bias[j];
    for (int f = 0; f < 2080; ++f) acc += hb[f] * wj[f];
    out[b * 128 + j] = tanhf(acc);
}

// ---------------- fc2: (B,128) @ (16,128)^T + b -> tanh -> (B,16) ----------------
__global__ void fc2_kernel(const float* __restrict__ h,
                           const float* __restrict__ w,
                           const float* __restrict__ bias,
                           float* __restrict__ out)
{
    int idx = blockIdx.x * blockDim.x + threadIdx.x;
    if (idx >= BATCH * 16) return;
    int b = idx / 16, j = idx % 16;
    const float* hb = h + (size_t)b * 128;
    const float* wj = w + (size_t)j * 128;
    float acc = bias[j];
#pragma unroll
    for (int f = 0; f < 128; ++f) acc += hb[f] * wj[f];
    out[idx] = tanhf(acc);
}

extern "C" void kernel_launch(void* const* d_in, const int* in_sizes, int n_in,
                              void* d_out, int out_size, void* d_ws, size_t ws_size,
                              hipStream_t stream)
{
    const float* x = (const float*)d_in[0];
    const int* orderings = (const int*)d_in[1];
    const float* sp_w = (const float*)d_in[2];
    const float* sp_b = (const float*)d_in[3];
    const float* conv_w[5];
    const float* conv_b[5];
    for (int j = 0; j < 5; ++j) {
        conv_w[j] = (const float*)d_in[4 + 2 * j];
        conv_b[j] = (const float*)d_in[5 + 2 * j];
    }
    const float* fc1_w = (const float*)d_in[14];
    const float* fc1_b = (const float*)d_in[15];
    const float* fc2_w = (const float*)d_in[16];
    const float* fc2_b = (const float*)d_in[17];

    float* ws = (float*)d_ws;
    // float offsets into workspace
    size_t o_s  = 0;                   // smoothed: 32*2*65536   = 4,194,304
    size_t o_c0 = o_s  + 4194304;      // conv0:    32*4*16385   = 2,097,280
    size_t o_c1 = o_c0 + 2097280;      // conv1:    32*8*4097    = 1,048,832
    size_t o_c2 = o_c1 + 1048832;      // conv2:    32*16*1025   =   524,800
    size_t o_c3 = o_c2 + 524800;       // conv3:    32*16*257    =   131,584
    size_t o_f  = o_c3 + 131584;       // feats:    32*2080      =    66,560
    size_t o_h1 = o_f  + 66560;        // h1:       32*128       =     4,096
    // total ~8.07M floats ~= 32.3 MB

    for (int i = 0; i < 2; ++i) {
        smooth_kernel<<<(BATCH * NPTS + 255) / 256, 256, 0, stream>>>(
            x, orderings + (size_t)i * NPTS, sp_w, sp_b, ws + o_s);

        conv_kernel<2, 4, 65536, 16385><<<(32 * 4 * 16385 + 255) / 256, 256, 0, stream>>>(
            ws + o_s, conv_w[0], conv_b[0], ws + o_c0, 4 * 16385);
        conv_kernel<4, 8, 16385, 4097><<<(32 * 8 * 4097 + 255) / 256, 256, 0, stream>>>(
            ws + o_c0, conv_w[1], conv_b[1], ws + o_c1, 8 * 4097);
        conv_kernel<8, 16, 4097, 1025><<<(32 * 16 * 1025 + 255) / 256, 256, 0, stream>>>(
            ws + o_c1, conv_w[2], conv_b[2], ws + o_c2, 16 * 1025);
        conv_kernel<16, 16, 1025, 257><<<(32 * 16 * 257 + 255) / 256, 256, 0, stream>>>(
            ws + o_c2, conv_w[3], conv_b[3], ws + o_c3, 16 * 257);
        // final conv writes directly into the concatenated feats buffer:
        // feats[b][i*1040 + co*65 + l], batch stride 2080
        conv_kernel<16, 16, 257, 65><<<(32 * 16 * 65 + 255) / 256, 256, 0, stream>>>(
            ws + o_c3, conv_w[4], conv_b[4], ws + o_f + (size_t)i * 1040, 2080);
    }

    fc1_kernel<<<32, 128, 0, stream>>>(ws + o_f, fc1_w, fc1_b, ws + o_h1);
    fc2_kernel<<<(BATCH * 16 + 255) / 256, 256, 0, stream>>>(ws + o_h1, fc2_w, fc2_b, (float*)d_out);
}

// Round 2
// 451.855 us; speedup vs baseline: 2.8849x; 2.8849x over previous
//
#include <hip/hip_runtime.h>
#include <math.h>

#define NPTS 65536
#define BATCH 32

// =====================================================================
// Tiled strided conv1d (+optional fused SFC-gather+smooth) + bias + tanh
//   out[b][co][l] = tanh(bias[co] + sum_{ci,k} in[b][ci][4l-16+k] * w[co][ci][k])
// Block: 256 threads = 4 waves. Each wave owns one output channel
// (COB channels/block, WPC=4/COB waves per channel splitting l-range).
// Input tile + weights staged in LDS; compute reads are contiguous
// float4 (ds_read_b128) against wave-uniform weight float4 (broadcast).
// =====================================================================
template <int CIN, int COUT, int COB, int LIN, int LOUT, int TILE, bool FUSE_SMOOTH>
__global__ __launch_bounds__(256) void conv_tiled(
    const float* __restrict__ in,      // FUSE_SMOOTH ? x (B,N,2) : (B,CIN,LIN)
    const int* __restrict__ ord,       // FUSE_SMOOTH only
    const float* __restrict__ sp_w,    // FUSE_SMOOTH only
    const float* __restrict__ sp_b,    // FUSE_SMOOTH only
    const float* __restrict__ w,       // (COUT, CIN, 32)
    const float* __restrict__ bias,    // (COUT,)
    float* __restrict__ out,           // out[b*out_bstride + co*LOUT + l]
    int out_bstride)
{
    constexpr int SPAN = 4 * TILE + 28;           // staged input floats per ci
    constexpr int NT = (LOUT + TILE - 1) / TILE;  // tiles along l
    constexpr int NCG = COUT / COB;               // channel groups

    __shared__ float in_s[CIN][SPAN];
    __shared__ float w_s[COB][CIN][32];

    int bid = blockIdx.x;
    int cog = bid % NCG;
    int tmp = bid / NCG;
    int tile = tmp % NT;
    int b = tmp / NT;
    int tid = threadIdx.x;

    // ---- stage weights (COB*CIN*32 floats, coalesced) ----
    for (int idx = tid; idx < COB * CIN * 32; idx += 256)
        ((float*)w_s)[idx] = w[cog * COB * CIN * 32 + idx];

    int base = tile * TILE * 4 - 16;  // global input pos of in_s[ci][0]

    // ---- stage input tile (zero-padded) ----
    if constexpr (FUSE_SMOOTH) {
        // in_s[c][p] = tanh(sum_k x[b, ord[clip(pos-1+k)], c]*sp_w[pos,k] + sp_b[pos])
        const float* xb = in + (size_t)b * NPTS * 2;
        for (int p = tid; p < SPAN; p += 256) {
            int pos = base + p;
            float c0 = 0.f, c1 = 0.f;
            if (pos >= 0 && pos < LIN) {
                int nm = (pos > 0) ? pos - 1 : 0;
                int np = (pos < LIN - 1) ? pos + 1 : LIN - 1;
                int i0 = ord[nm], i1 = ord[pos], i2 = ord[np];
                float w0 = sp_w[pos * 3 + 0];
                float w1 = sp_w[pos * 3 + 1];
                float w2 = sp_w[pos * 3 + 2];
                float bb = sp_b[pos];
                float2 v0 = *(const float2*)(xb + (size_t)i0 * 2);
                float2 v1 = *(const float2*)(xb + (size_t)i1 * 2);
                float2 v2 = *(const float2*)(xb + (size_t)i2 * 2);
                c0 = tanhf(v0.x * w0 + v1.x * w1 + v2.x * w2 + bb);
                c1 = tanhf(v0.y * w0 + v1.y * w1 + v2.y * w2 + bb);
            }
            in_s[0][p] = c0;
            in_s[1][p] = c1;
        }
    } else {
        for (int ci = 0; ci < CIN; ++ci) {
            const float* inc = in + ((size_t)b * CIN + ci) * LIN;
            for (int p = tid; p < SPAN; p += 256) {
                int pos = base + p;
                in_s[ci][p] = (pos >= 0 && pos < LIN) ? inc[pos] : 0.f;
            }
        }
    }
    __syncthreads();

    // ---- compute ----
    constexpr int WPC = 4 / COB;        // waves per output channel
    constexpr int LSTRIDE = 64 * WPC;   // l positions covered per j step
    constexpr int JMAX = (TILE + LSTRIDE - 1) / LSTRIDE;

    int lane = tid & 63;
    int wv = tid >> 6;
    int co_l = wv / WPC;                // channel within group
    int lseg = wv % WPC;
    int co = cog * COB + co_l;
    int lbase = lane + lseg * 64;       // offset within tile for j=0

    float acc[JMAX];
    float bv = bias[co];
#pragma unroll
    for (int j = 0; j < JMAX; ++j) acc[j] = bv;

    for (int ci = 0; ci < CIN; ++ci) {
#pragma unroll
        for (int k4 = 0; k4 < 8; ++k4) {
            float4 wv4 = *(const float4*)&w_s[co_l][ci][k4 * 4];
#pragma unroll
            for (int j = 0; j < JMAX; ++j) {
                int lofs = lbase + j * LSTRIDE;
                if (lofs < TILE) {
                    float4 iv = *(const float4*)&in_s[ci][4 * lofs + 4 * k4];
                    acc[j] += iv.x * wv4.x + iv.y * wv4.y + iv.z * wv4.z + iv.w * wv4.w;
                }
            }
        }
    }

#pragma unroll
    for (int j = 0; j < JMAX; ++j) {
        int lofs = lbase + j * LSTRIDE;
        int l = tile * TILE + lofs;
        if (lofs < TILE && l < LOUT)
            out[(size_t)b * out_bstride + co * LOUT + l] = tanhf(acc[j]);
    }
}

// =====================================================================
// fc1: (32,2080) @ (128,2080)^T + b -> tanh. One wave per output, f-parallel.
// =====================================================================
__global__ __launch_bounds__(256) void fc1_kernel(const float* __restrict__ h,
                                                  const float* __restrict__ w,
                                                  const float* __restrict__ bias,
                                                  float* __restrict__ out)
{
    int lane = threadIdx.x & 63;
    int wid = blockIdx.x * 4 + (threadIdx.x >> 6);  // 0..1023
#pragma unroll
    for (int r = 0; r < 4; ++r) {
        int o = wid + r * 1024;   // 0..4095
        int b = o >> 7;
        int j = o & 127;
        const float* hb = h + (size_t)b * 2080;
        const float* wj = w + (size_t)j * 2080;
        float acc = 0.f;
        for (int f = lane; f < 2080; f += 64) acc += hb[f] * wj[f];
        for (int off = 32; off; off >>= 1) acc += __shfl_down(acc, off, 64);
        if (lane == 0) out[b * 128 + j] = tanhf(acc + bias[j]);
    }
}

// =====================================================================
// fc2: (32,128) @ (16,128)^T + b -> tanh. One wave per output.
// =====================================================================
__global__ __launch_bounds__(256) void fc2_kernel(const float* __restrict__ h,
                                                  const float* __restrict__ w,
                                                  const float* __restrict__ bias,
                                                  float* __restrict__ out)
{
    int lane = threadIdx.x & 63;
    int o = blockIdx.x * 4 + (threadIdx.x >> 6);  // 0..511
    int b = o >> 4;
    int j = o & 15;
    const float* hb = h + (size_t)b * 128;
    const float* wj = w + (size_t)j * 128;
    float acc = hb[lane] * wj[lane] + hb[lane + 64] * wj[lane + 64];
    for (int off = 32; off; off >>= 1) acc += __shfl_down(acc, off, 64);
    if (lane == 0) out[o] = tanhf(acc + bias[j]);
}

extern "C" void kernel_launch(void* const* d_in, const int* in_sizes, int n_in,
                              void* d_out, int out_size, void* d_ws, size_t ws_size,
                              hipStream_t stream)
{
    const float* x = (const float*)d_in[0];
    const int* orderings = (const int*)d_in[1];
    const float* sp_w = (const float*)d_in[2];
    const float* sp_b = (const float*)d_in[3];
    const float* conv_w[5];
    const float* conv_b[5];
    for (int j = 0; j < 5; ++j) {
        conv_w[j] = (const float*)d_in[4 + 2 * j];
        conv_b[j] = (const float*)d_in[5 + 2 * j];
    }
    const float* fc1_w = (const float*)d_in[14];
    const float* fc1_b = (const float*)d_in[15];
    const float* fc2_w = (const float*)d_in[16];
    const float* fc2_b = (const float*)d_in[17];

    float* ws = (float*)d_ws;
    size_t o_c0 = 0;                   // conv0 out: 32*4*16385 = 2,097,280
    size_t o_c1 = o_c0 + 2097280;      // conv1 out: 32*8*4097  = 1,048,832
    size_t o_c2 = o_c1 + 1048832;      // conv2 out: 32*16*1025 =   524,800
    size_t o_c3 = o_c2 + 524800;       // conv3 out: 32*16*257  =   131,584
    size_t o_f  = o_c3 + 131584;       // feats:     32*2080    =    66,560
    size_t o_h1 = o_f  + 66560;        // h1:        32*128     =     4,096

    for (int i = 0; i < 2; ++i) {
        const int* ord = orderings + (size_t)i * NPTS;

        // conv0 (+fused gather/smooth/tanh): CIN=2,COUT=4,COB=4,TILE=256
        // grid = B * NT * NCG = 32*65*1
        conv_tiled<2, 4, 4, 65536, 16385, 256, true><<<32 * 65 * 1, 256, 0, stream>>>(
            x, ord, sp_w, sp_b, conv_w[0], conv_b[0], ws + o_c0, 4 * 16385);

        // conv1: CIN=4,COUT=8,COB=4,TILE=256  grid = 32*17*2
        conv_tiled<4, 8, 4, 16385, 4097, 256, false><<<32 * 17 * 2, 256, 0, stream>>>(
            ws + o_c0, nullptr, nullptr, nullptr, conv_w[1], conv_b[1], ws + o_c1, 8 * 4097);

        // conv2: CIN=8,COUT=16,COB=4,TILE=256  grid = 32*5*4
        conv_tiled<8, 16, 4, 4097, 1025, 256, false><<<32 * 5 * 4, 256, 0, stream>>>(
            ws + o_c1, nullptr, nullptr, nullptr, conv_w[2], conv_b[2], ws + o_c2, 16 * 1025);

        // conv3: CIN=16,COUT=16,COB=2,TILE=257  grid = 32*1*8
        conv_tiled<16, 16, 2, 1025, 257, 257, false><<<32 * 1 * 8, 256, 0, stream>>>(
            ws + o_c2, nullptr, nullptr, nullptr, conv_w[3], conv_b[3], ws + o_c3, 16 * 257);

        // conv4: CIN=16,COUT=16,COB=2,TILE=65  grid = 32*1*8
        // writes into feats[b][i*1040 + co*65 + l], batch stride 2080
        conv_tiled<16, 16, 2, 257, 65, 65, false><<<32 * 1 * 8, 256, 0, stream>>>(
            ws + o_c3, nullptr, nullptr, nullptr, conv_w[4], conv_b[4],
            ws + o_f + (size_t)i * 1040, 2080);
    }

    fc1_kernel<<<256, 256, 0, stream>>>(ws + o_f, fc1_w, fc1_b, ws + o_h1);
    fc2_kernel<<<128, 256, 0, stream>>>(ws + o_h1, fc2_w, fc2_b, (float*)d_out);
}

// Round 3
// 354.021 us; speedup vs baseline: 3.6821x; 1.2764x over previous
//
#include <hip/hip_runtime.h>
#include <math.h>

#define NPTS 65536
#define BATCH 32

// =====================================================================
// transpose x (B,N,2) -> x_t (N, 64)  [x_t[n][b*2+c] = x[b][n][c]]
// =====================================================================
__global__ __launch_bounds__(256) void transpose_kernel(const float* __restrict__ x,
                                                        float* __restrict__ xt)
{
    __shared__ float tile[64][65];
    int n0 = blockIdx.x * 64;
    int tid = threadIdx.x;
    int lane = tid & 63, w = tid >> 6;
    const float2* x2 = (const float2*)x;
#pragma unroll
    for (int bq = 0; bq < 8; ++bq) {
        int b = bq * 4 + w;
        float2 v = x2[(size_t)b * NPTS + n0 + lane];
        tile[lane][b * 2 + 0] = v.x;
        tile[lane][b * 2 + 1] = v.y;
    }
    __syncthreads();
#pragma unroll
    for (int rq = 0; rq < 16; ++rq) {
        int r = rq * 4 + w;
        xt[(size_t)(n0 + r) * 64 + lane] = tile[r][lane];
    }
}

// =====================================================================
// smooth: s[(i*64 + b*2+c)][n] = tanh(sum_k x_t[ord_i[clip(n-1+k)]][b*2+c]*sp_w[n,k] + sp_b[n])
// Block handles one SFC i and 128 consecutive n, all 64 (b,c).
// Row-gather from x_t: 256B contiguous per row, staged in LDS.
// =====================================================================
__global__ __launch_bounds__(256) void smooth_kernel(const float* __restrict__ xt,
                                                     const int* __restrict__ orderings,
                                                     const float* __restrict__ sp_w,
                                                     const float* __restrict__ sp_b,
                                                     float* __restrict__ s)
{
    constexpr int TILE_N = 128;
    __shared__ int s_idx[TILE_N + 2];
    __shared__ float rows[TILE_N + 2][65];

    int bid = blockIdx.x;
    int i = bid >> 9;          // 512 tiles per SFC
    int t = bid & 511;
    int n0 = t * TILE_N;
    int tid = threadIdx.x;
    const int* ord = orderings + (size_t)i * NPTS;

    if (tid < TILE_N + 2) {
        int g = n0 - 1 + tid;
        g = g < 0 ? 0 : (g > NPTS - 1 ? NPTS - 1 : g);
        s_idx[tid] = ord[g];
    }
    __syncthreads();

    int lane = tid & 63, w = tid >> 6;
    for (int r = w; r < TILE_N + 2; r += 4)
        rows[r][lane] = xt[(size_t)s_idx[r] * 64 + lane];
    __syncthreads();

    int n_local = tid & 127;
    int half = tid >> 7;       // 0 or 1
    int n = n0 + n_local;
    float w0 = sp_w[n * 3 + 0], w1 = sp_w[n * 3 + 1], w2 = sp_w[n * 3 + 2];
    float bb = sp_b[n];
#pragma unroll 4
    for (int bc = 0; bc < 64; bc += 2) {
        int bce = bc + half;
        float v = w0 * rows[n_local][bce] + w1 * rows[n_local + 1][bce]
                + w2 * rows[n_local + 2][bce] + bb;
        s[(size_t)(i * 64 + bce) * NPTS + n] = tanhf(v);
    }
}

// =====================================================================
// Tiled strided conv1d + bias + tanh, batch merged over both SFC (b = 0..63).
// =====================================================================
template <int CIN, int COUT, int COB, int LIN, int LOUT, int TILE, bool CONCAT>
__global__ __launch_bounds__(256) void conv_tiled(
    const float* __restrict__ in,      // (64, CIN, LIN)
    const float* __restrict__ w,       // (COUT, CIN, 32)
    const float* __restrict__ bias,    // (COUT,)
    float* __restrict__ out)
{
    constexpr int SPAN = 4 * TILE + 28;
    constexpr int NT = (LOUT + TILE - 1) / TILE;
    constexpr int NCG = COUT / COB;

    __shared__ float in_s[CIN][SPAN];
    __shared__ float w_s[COB][CIN][32];

    int bid = blockIdx.x;
    int cog = bid % NCG;
    int tmp = bid / NCG;
    int tile = tmp % NT;
    int b = tmp / NT;
    int tid = threadIdx.x;

    for (int idx = tid; idx < COB * CIN * 32; idx += 256)
        ((float*)w_s)[idx] = w[cog * COB * CIN * 32 + idx];

    int base = tile * TILE * 4 - 16;

    for (int ci = 0; ci < CIN; ++ci) {
        const float* inc = in + ((size_t)b * CIN + ci) * LIN;
        for (int p = tid; p < SPAN; p += 256) {
            int pos = base + p;
            in_s[ci][p] = (pos >= 0 && pos < LIN) ? inc[pos] : 0.f;
        }
    }
    __syncthreads();

    constexpr int WPC = 4 / COB;
    constexpr int LSTRIDE = 64 * WPC;
    constexpr int JMAX = (TILE + LSTRIDE - 1) / LSTRIDE;

    int lane = tid & 63;
    int wv = tid >> 6;
    int co_l = wv / WPC;
    int lseg = wv % WPC;
    int co = cog * COB + co_l;
    int lbase = lane + lseg * 64;

    float acc[JMAX];
    float bv = bias[co];
#pragma unroll
    for (int j = 0; j < JMAX; ++j) acc[j] = bv;

    for (int ci = 0; ci < CIN; ++ci) {
#pragma unroll
        for (int k4 = 0; k4 < 8; ++k4) {
            float4 wv4 = *(const float4*)&w_s[co_l][ci][k4 * 4];
#pragma unroll
            for (int j = 0; j < JMAX; ++j) {
                int lofs = lbase + j * LSTRIDE;
                if (lofs < TILE) {
                    float4 iv = *(const float4*)&in_s[ci][4 * lofs + 4 * k4];
                    acc[j] += iv.x * wv4.x + iv.y * wv4.y + iv.z * wv4.z + iv.w * wv4.w;
                }
            }
        }
    }

#pragma unroll
    for (int j = 0; j < JMAX; ++j) {
        int lofs = lbase + j * LSTRIDE;
        int l = tile * TILE + lofs;
        if (lofs < TILE && l < LOUT) {
            float r = tanhf(acc[j]);
            if constexpr (CONCAT) {
                // b = i*32 + batch; feats[batch][i*1040 + co*65 + l]
                out[(size_t)(b & 31) * 2080 + (b >> 5) * 1040 + co * 65 + l] = r;
            } else {
                out[(size_t)b * (COUT * LOUT) + co * LOUT + l] = r;
            }
        }
    }
}

// =====================================================================
// fc1: (32,2080) @ (128,2080)^T + b -> tanh. One wave per output, f-parallel.
// =====================================================================
__global__ __launch_bounds__(256) void fc1_kernel(const float* __restrict__ h,
                                                  const float* __restrict__ w,
                                                  const float* __restrict__ bias,
                                                  float* __restrict__ out)
{
    int lane = threadIdx.x & 63;
    int wid = blockIdx.x * 4 + (threadIdx.x >> 6);  // 0..1023
#pragma unroll
    for (int r = 0; r < 4; ++r) {
        int o = wid + r * 1024;   // 0..4095
        int b = o >> 7;
        int j = o & 127;
        const float* hb = h + (size_t)b * 2080;
        const float* wj = w + (size_t)j * 2080;
        float acc = 0.f;
        for (int f = lane; f < 2080; f += 64) acc += hb[f] * wj[f];
        for (int off = 32; off; off >>= 1) acc += __shfl_down(acc, off, 64);
        if (lane == 0) out[b * 128 + j] = tanhf(acc + bias[j]);
    }
}

// =====================================================================
// fc2: (32,128) @ (16,128)^T + b -> tanh. One wave per output.
// =====================================================================
__global__ __launch_bounds__(256) void fc2_kernel(const float* __restrict__ h,
                                                  const float* __restrict__ w,
                                                  const float* __restrict__ bias,
                                                  float* __restrict__ out)
{
    int lane = threadIdx.x & 63;
    int o = blockIdx.x * 4 + (threadIdx.x >> 6);  // 0..511
    int b = o >> 4;
    int j = o & 15;
    const float* hb = h + (size_t)b * 128;
    const float* wj = w + (size_t)j * 128;
    float acc = hb[lane] * wj[lane] + hb[lane + 64] * wj[lane + 64];
    for (int off = 32; off; off >>= 1) acc += __shfl_down(acc, off, 64);
    if (lane == 0) out[o] = tanhf(acc + bias[j]);
}

extern "C" void kernel_launch(void* const* d_in, const int* in_sizes, int n_in,
                              void* d_out, int out_size, void* d_ws, size_t ws_size,
                              hipStream_t stream)
{
    const float* x = (const float*)d_in[0];
    const int* orderings = (const int*)d_in[1];
    const float* sp_w = (const float*)d_in[2];
    const float* sp_b = (const float*)d_in[3];
    const float* conv_w[5];
    const float* conv_b[5];
    for (int j = 0; j < 5; ++j) {
        conv_w[j] = (const float*)d_in[4 + 2 * j];
        conv_b[j] = (const float*)d_in[5 + 2 * j];
    }
    const float* fc1_w = (const float*)d_in[14];
    const float* fc1_b = (const float*)d_in[15];
    const float* fc2_w = (const float*)d_in[16];
    const float* fc2_b = (const float*)d_in[17];

    float* ws = (float*)d_ws;
    // Region A: [0, 4194560)        x_t (4,194,304) then conv0-out (4,194,560), then conv3-out + feats + h1
    // Region B: [4194560, 12583168) s (8,388,608), then conv1-out, conv2-out
    size_t o_A = 0;
    size_t o_B = 4194560;
    size_t o_c2 = o_B + 2097664;       // conv2 out after conv1 out in region B
    size_t o_f  = o_A + 263168;        // feats after conv3 out in region A
    size_t o_h1 = o_f + 66560;         // h1

    // 1) transpose x -> x_t (region A)
    transpose_kernel<<<NPTS / 64, 256, 0, stream>>>(x, ws + o_A);

    // 2) smooth both SFC -> s (region B), layout (i*64 + b*2+c, N)
    smooth_kernel<<<2 * 512, 256, 0, stream>>>(ws + o_A, orderings, sp_w, sp_b, ws + o_B);

    // 3) conv0: in s (b_eff=64, CIN=2, LIN=65536) -> region A
    conv_tiled<2, 4, 4, 65536, 16385, 256, false><<<64 * 65 * 1, 256, 0, stream>>>(
        ws + o_B, conv_w[0], conv_b[0], ws + o_A);

    // 4) conv1: region A -> region B
    conv_tiled<4, 8, 4, 16385, 4097, 256, false><<<64 * 17 * 2, 256, 0, stream>>>(
        ws + o_A, conv_w[1], conv_b[1], ws + o_B);

    // 5) conv2: region B -> region B (after conv1 out)
    conv_tiled<8, 16, 4, 4097, 1025, 256, false><<<64 * 5 * 4, 256, 0, stream>>>(
        ws + o_B, conv_w[2], conv_b[2], ws + o_c2);

    // 6) conv3: -> region A
    conv_tiled<16, 16, 2, 1025, 257, 257, false><<<64 * 1 * 8, 256, 0, stream>>>(
        ws + o_c2, conv_w[3], conv_b[3], ws + o_A);

    // 7) conv4 (CONCAT into feats)
    conv_tiled<16, 16, 2, 257, 65, 65, true><<<64 * 1 * 8, 256, 0, stream>>>(
        ws + o_A, conv_w[4], conv_b[4], ws + o_f);

    fc1_kernel<<<256, 256, 0, stream>>>(ws + o_f, fc1_w, fc1_b, ws + o_h1);
    fc2_kernel<<<128, 256, 0, stream>>>(ws + o_h1, fc2_w, fc2_b, (float*)d_out);
}